// Round 3
// baseline (359.611 us; speedup 1.0000x reference)
//
#include <hip/hip_runtime.h>

#define NB 16384
#define NT 512
#define NL 4
#define NH 2
#define NRET (NB*NT*NH)
#define TC 8

// Swap lanes within pairs (lane 2k <-> 2k+1): DPP quad_perm [1,0,3,2] = 0xB1.
__device__ __forceinline__ float swap1(float x) {
  return __int_as_float(__builtin_amdgcn_mov_dpp(__float_as_int(x), 0xB1, 0xF, 0xF, true));
}
__device__ __forceinline__ float rcp1p(float e) {   // 1/(1+e)
  return __builtin_amdgcn_rcpf(1.0f + e);
}

// 2 lanes per batch element (lane j owns hidden unit j) x 2 chains per lane.
// The two chains' cell DAGs interleave in the instruction stream so trans/FMA
// latency of one chain is hidden under the other's issue: wall/cell -> issue
// floor (~132cy) instead of dep-chain latency (~230cy, R2 measurement).
__global__ __launch_bounds__(64, 1) void lstm_k(
    const float* __restrict__ inp, const float* __restrict__ lab,
    const float* __restrict__ Wih, const float* __restrict__ Whh,
    const float* __restrict__ bhh, float* __restrict__ out)
{
  __shared__ __align__(16) float lds[64][TC*NH];  // 4 KB: 64 chains x 8 steps x 2
  const int tid = threadIdx.x;
  const int el = tid >> 1, j = tid & 1, jo = j ^ 1;
  const int b0 = blockIdx.x << 6;                 // 64 chains per block
  const int bA = b0 + el, bB = b0 + 32 + el;

  const float K1 = 1.4426950408889634f;   // log2(e)
  const float K2 = 2.8853900817779268f;   // 2 log2(e)
  const float K4 = 5.7707801635558536f;   // 4 log2(e)

  // Scales folded into weights (sigma rows x -log2e, tanh row x -2log2e);
  // c lives in the scaled domain c~ = -2log2e*c. Weights SHARED by both chains.
  float wio[NL][4], wix[NL][4], who[NL][4], whx[NL][4], bi[NL][4];
  #pragma unroll
  for (int l = 0; l < NL; ++l) {
    #pragma unroll
    for (int g = 0; g < 4; ++g) {
      const int row = l*8 + g*2 + j;         // torch rows [i i f f g g o o]
      const float s = (g == 2) ? -K2 : -K1;
      wio[l][g] = s * Wih[row*2 + j];
      wix[l][g] = s * Wih[row*2 + jo];
      who[l][g] = s * Whh[row*2 + j];
      whx[l][g] = s * Whh[row*2 + jo];
      bi[l][g]  = s * bhh[row];
    }
  }
  // Pin the 80 scaled weights: opaque redefinition makes remat of the global
  // loads illegal, so the allocator must keep them VGPR-resident instead of
  // re-loading inside the serial recurrence (R1/R2: VGPR_Count stuck at 68).
  #pragma unroll
  for (int l = 0; l < NL; ++l)
    asm volatile("" :
      "+v"(wio[l][0]), "+v"(wio[l][1]), "+v"(wio[l][2]), "+v"(wio[l][3]),
      "+v"(wix[l][0]), "+v"(wix[l][1]), "+v"(wix[l][2]), "+v"(wix[l][3]),
      "+v"(who[l][0]), "+v"(who[l][1]), "+v"(who[l][2]), "+v"(who[l][3]),
      "+v"(whx[l][0]), "+v"(whx[l][1]), "+v"(whx[l][2]), "+v"(whx[l][3]),
      "+v"(bi[l][0]),  "+v"(bi[l][1]),  "+v"(bi[l][2]),  "+v"(bi[l][3]));

  float partA[NL][4], partB[NL][4], cA[NL], cB[NL];
  #pragma unroll
  for (int l = 0; l < NL; ++l) {
    cA[l] = 0.f; cB[l] = 0.f;
    #pragma unroll
    for (int g = 0; g < 4; ++g) { partA[l][g] = bi[l][g]; partB[l][g] = bi[l][g]; }
  }

  float xoA = inp[bA*NH + j], xxA = inp[bA*NH + jo];
  float xoB = inp[bB*NH + j], xxB = inp[bB*NH + jo];
  float lsum = 0.f;

  for (int t0 = 0; t0 < NT; t0 += TC) {
    // Prefetch this chunk's labels (~1200 cy of compute covers HBM latency).
    float4 lv[4];
    #pragma unroll
    for (int q = 0; q < 4; ++q) {
      const int f = q*64 + tid, e = f >> 2, p = f & 3;
      lv[q] = ((const float4*)(lab + (size_t)(b0 + e) * (NT*NH) + (size_t)t0*NH))[p];
    }

    #pragma unroll
    for (int tl = 0; tl < TC; ++tl) {
      #pragma unroll
      for (int l = 0; l < NL; ++l) {
        // ---- chain A, layer l ----
        float a0 = fmaf(wix[l][0], xxA, fmaf(wio[l][0], xoA, partA[l][0]));
        float a1 = fmaf(wix[l][1], xxA, fmaf(wio[l][1], xoA, partA[l][1]));
        float a2 = fmaf(wix[l][2], xxA, fmaf(wio[l][2], xoA, partA[l][2]));
        float a3 = fmaf(wix[l][3], xxA, fmaf(wio[l][3], xoA, partA[l][3]));
        // ---- chain B, layer l (independent DAG: fills A's latency gaps) ----
        float b0g = fmaf(wix[l][0], xxB, fmaf(wio[l][0], xoB, partB[l][0]));
        float b1g = fmaf(wix[l][1], xxB, fmaf(wio[l][1], xoB, partB[l][1]));
        float b2g = fmaf(wix[l][2], xxB, fmaf(wio[l][2], xoB, partB[l][2]));
        float b3g = fmaf(wix[l][3], xxB, fmaf(wio[l][3], xoB, partB[l][3]));

        float piA = rcp1p(__builtin_amdgcn_exp2f(a0));
        float pfA = rcp1p(__builtin_amdgcn_exp2f(a1));
        float r2A = rcp1p(__builtin_amdgcn_exp2f(a2));
        float poA = rcp1p(__builtin_amdgcn_exp2f(a3));
        float piB = rcp1p(__builtin_amdgcn_exp2f(b0g));
        float pfB = rcp1p(__builtin_amdgcn_exp2f(b1g));
        float r2B = rcp1p(__builtin_amdgcn_exp2f(b2g));
        float poB = rcp1p(__builtin_amdgcn_exp2f(b3g));

        float tgA = fmaf(-K4, r2A, K2);
        float tgB = fmaf(-K4, r2B, K2);
        cA[l] = fmaf(pfA, cA[l], piA * tgA);
        cB[l] = fmaf(pfB, cB[l], piB * tgB);
        float rcA = rcp1p(__builtin_amdgcn_exp2f(cA[l]));
        float rcB = rcp1p(__builtin_amdgcn_exp2f(cB[l]));
        float nhA = fmaf(poA + poA, rcA, -poA);
        float nhB = fmaf(poB + poB, rcB, -poB);
        float nsA = swap1(nhA);
        float nsB = swap1(nhB);
        // Next-step h-partials: off the critical path (full step of slack).
        partA[l][0] = fmaf(whx[l][0], nsA, fmaf(who[l][0], nhA, bi[l][0]));
        partA[l][1] = fmaf(whx[l][1], nsA, fmaf(who[l][1], nhA, bi[l][1]));
        partA[l][2] = fmaf(whx[l][2], nsA, fmaf(who[l][2], nhA, bi[l][2]));
        partA[l][3] = fmaf(whx[l][3], nsA, fmaf(who[l][3], nhA, bi[l][3]));
        partB[l][0] = fmaf(whx[l][0], nsB, fmaf(who[l][0], nhB, bi[l][0]));
        partB[l][1] = fmaf(whx[l][1], nsB, fmaf(who[l][1], nhB, bi[l][1]));
        partB[l][2] = fmaf(whx[l][2], nsB, fmaf(who[l][2], nhB, bi[l][2]));
        partB[l][3] = fmaf(whx[l][3], nsB, fmaf(who[l][3], nhB, bi[l][3]));
        xoA = nhA; xxA = nsA;
        xoB = nhB; xxB = nsB;
      }
      lds[el][tl*NH + j]      = xoA;       // stage layer-3 h_j, chain A
      lds[32 + el][tl*NH + j] = xoB;       // chain B
    }
    __syncthreads();
    // Coalesced flush; labels already in registers.
    const float4* lf = (const float4*)&lds[0][0];
    #pragma unroll
    for (int q = 0; q < 4; ++q) {
      const int f = q*64 + tid, e = f >> 2, p = f & 3;
      float4 v = lf[f];
      float4* o4 = (float4*)(out + (size_t)(b0 + e) * (NT*NH) + (size_t)t0*NH);
      o4[p] = v;
      float d0 = v.x - lv[q].x, d1 = v.y - lv[q].y,
            d2 = v.z - lv[q].z, d3 = v.w - lv[q].w;
      lsum = fmaf(d0,d0, fmaf(d1,d1, fmaf(d2,d2, fmaf(d3,d3, lsum))));
    }
    __syncthreads();
  }

  #pragma unroll
  for (int off = 32; off >= 1; off >>= 1)
    lsum += __shfl_xor(lsum, off, 64);
  if (tid == 0)
    atomicAdd(out + NRET, lsum * (1.0f / (float)NRET));
}

extern "C" void kernel_launch(void* const* d_in, const int* in_sizes, int n_in,
                              void* d_out, int out_size, void* d_ws, size_t ws_size,
                              hipStream_t stream) {
  const float* inp = (const float*)d_in[0];
  const float* lab = (const float*)d_in[1];
  const float* Wih = (const float*)d_in[2];
  const float* Whh = (const float*)d_in[3];
  const float* bhh = (const float*)d_in[4];
  float* out = (float*)d_out;
  // loss slot must be re-zeroed every launch (harness does not re-poison)
  hipMemsetAsync(out + NRET, 0, sizeof(float), stream);
  lstm_k<<<NB/64, 64, 0, stream>>>(inp, lab, Wih, Whh, bhh, out);
}

// Round 5
// 302.556 us; speedup vs baseline: 1.1886x; 1.1886x over previous
//
#include <hip/hip_runtime.h>

#define NB 16384
#define NT 512
#define NL 4
#define NH 2
#define NRET (NB*NT*NH)
#define TC 8

typedef float vf2 __attribute__((ext_vector_type(2)));

// Swap lanes within pairs (lane 2k <-> 2k+1): DPP quad_perm [1,0,3,2] = 0xB1.
__device__ __forceinline__ float swap1(float x) {
  return __int_as_float(__builtin_amdgcn_mov_dpp(__float_as_int(x), 0xB1, 0xF, 0xF, true));
}
__device__ __forceinline__ vf2 sp(float s) { vf2 r; r.x = s; r.y = s; return r; }
__device__ __forceinline__ vf2 vexp2(vf2 x) {
  vf2 r; r.x = __builtin_amdgcn_exp2f(x.x); r.y = __builtin_amdgcn_exp2f(x.y); return r;
}
__device__ __forceinline__ vf2 vrcp(vf2 x) {
  vf2 r; r.x = __builtin_amdgcn_rcpf(x.x); r.y = __builtin_amdgcn_rcpf(x.y); return r;
}
__device__ __forceinline__ vf2 vfma_(vf2 a, vf2 b, vf2 c) { return __builtin_elementwise_fma(a, b, c); }
__device__ __forceinline__ vf2 vclamp(vf2 x, float lo, float hi) {
  return __builtin_elementwise_min(__builtin_elementwise_max(x, sp(lo)), sp(hi));
}
// tanh Pade(7,6): num/den returned separately so callers can fold the division
// into a shared rcp. Exact CF convergent; |err| < 2e-5 on |x|<=4.
__device__ __forceinline__ void pade76(vf2 x, vf2& n, vf2& d) {
  vf2 t = x * x;
  n = x * vfma_(t, vfma_(t, t + sp(378.f), sp(17325.f)), sp(135135.f));
  d = vfma_(t, vfma_(t, vfma_(t, sp(28.f), sp(3150.f)), sp(62370.f)), sp(135135.f));
}

// 2 lanes per batch element (lane j owns hidden unit j) x 2 chains per lane,
// chains packed in vf2 (.x = chain A, .y = chain B) so the compiler can emit
// v_pk_fma_f32. Math per cell: T=5 transcendentals (3 exp2 for sigma(i,f,o),
// 1 shared rcp for the c-update, 1 shared rcp for h) vs R2's 10 — R2/R3 fit
// shows wall/cell ~= 2*VALU + 16*TRANS, so trans count is the lever.
__global__ __launch_bounds__(64, 1) void lstm_k(
    const float* __restrict__ inp, const float* __restrict__ lab,
    const float* __restrict__ Wih, const float* __restrict__ Whh,
    const float* __restrict__ bhh, float* __restrict__ out)
{
  __shared__ float lds[64][TC*NH + 1];     // pad 16->17: kills 16-way store conflict
  const int tid = threadIdx.x;
  const int el = tid >> 1, j = tid & 1, jo = j ^ 1;
  const int b0 = blockIdx.x << 6;          // 64 chains per block
  const int bA = b0 + el, bB = b0 + 32 + el;

  const float K1 = 1.4426950408889634f;    // log2(e)

  // sigma rows (i,f,o) folded with -log2e so sigma = rcp(1+exp2(g~));
  // tanh row (g) kept RAW (Pade consumes true g). Weights shared by chains.
  float wio[NL][4], wix[NL][4], who[NL][4], whx[NL][4], bi[NL][4];
  #pragma unroll
  for (int l = 0; l < NL; ++l) {
    #pragma unroll
    for (int g = 0; g < 4; ++g) {
      const int row = l*8 + g*2 + j;       // torch rows [i i f f g g o o]
      const float s = (g == 2) ? 1.0f : -K1;
      wio[l][g] = s * Wih[row*2 + j];
      wix[l][g] = s * Wih[row*2 + jo];
      who[l][g] = s * Whh[row*2 + j];
      whx[l][g] = s * Whh[row*2 + jo];
      bi[l][g]  = s * bhh[row];
    }
  }
  // Pin scalars: forbids remat-from-global inside the recurrence (R1 lesson).
  #pragma unroll
  for (int l = 0; l < NL; ++l)
    asm volatile("" :
      "+v"(wio[l][0]), "+v"(wio[l][1]), "+v"(wio[l][2]), "+v"(wio[l][3]),
      "+v"(wix[l][0]), "+v"(wix[l][1]), "+v"(wix[l][2]), "+v"(wix[l][3]),
      "+v"(who[l][0]), "+v"(who[l][1]), "+v"(who[l][2]), "+v"(who[l][3]),
      "+v"(whx[l][0]), "+v"(whx[l][1]), "+v"(whx[l][2]), "+v"(whx[l][3]),
      "+v"(bi[l][0]),  "+v"(bi[l][1]),  "+v"(bi[l][2]),  "+v"(bi[l][3]));

  vf2 P[NL][4], C[NL];
  #pragma unroll
  for (int l = 0; l < NL; ++l) {
    C[l] = sp(0.f);
    #pragma unroll
    for (int g = 0; g < 4; ++g) P[l][g] = sp(bi[l][g]);   // h == c == 0 at t=0
  }

  vf2 XO, XX;
  XO.x = inp[bA*NH + j];  XO.y = inp[bB*NH + j];
  XX.x = inp[bA*NH + jo]; XX.y = inp[bB*NH + jo];
  float lsum = 0.f;

  for (int t0 = 0; t0 < NT; t0 += TC) {
    // Prefetch this chunk's labels; ~2400 cy of compute covers HBM latency.
    float4 lv[4];
    #pragma unroll
    for (int q = 0; q < 4; ++q) {
      const int f = q*64 + tid, e = f >> 2, p = f & 3;
      lv[q] = ((const float4*)(lab + (size_t)(b0 + e) * (NT*NH) + (size_t)t0*NH))[p];
    }

    #pragma unroll
    for (int tl = 0; tl < TC; ++tl) {
      #pragma unroll
      for (int l = 0; l < NL; ++l) {
        vf2 G0 = vfma_(XX, sp(wix[l][0]), vfma_(XO, sp(wio[l][0]), P[l][0])); // i~
        vf2 G1 = vfma_(XX, sp(wix[l][1]), vfma_(XO, sp(wio[l][1]), P[l][1])); // f~
        vf2 G2 = vfma_(XX, sp(wix[l][2]), vfma_(XO, sp(wio[l][2]), P[l][2])); // g raw
        vf2 G3 = vfma_(XX, sp(wix[l][3]), vfma_(XO, sp(wio[l][3]), P[l][3])); // o~
        vf2 EI = vexp2(G0), EF = vexp2(G1), EO = vexp2(G3);
        vf2 AI = EI + sp(1.f), AF = EF + sp(1.f), AO = EO + sp(1.f);
        // tanh(g), never divided: folded into the single c-update rcp.
        vf2 NG, DG;
        pade76(vclamp(G2, -4.f, 4.f), NG, DG);
        // c2 = sf*c + si*tanh(g) = [c*AI*DG + NG*AF] * rcp(AF*AI*DG)  (exact)
        vf2 Pm  = AI * DG;
        vf2 NUM = vfma_(NG, AF, C[l] * Pm);
        vf2 RD  = vrcp(Pm * AF);
        C[l] = NUM * RD;
        // h = so*tanh(c) = NC * rcp(QD*AO)  (exact given Pade tanh)
        vf2 NC, QD;
        pade76(vclamp(C[l], -5.f, 5.f), NC, QD);
        vf2 RH = vrcp(QD * AO);
        vf2 HN = NC * RH;                  // new h (own lane)
        vf2 HS; HS.x = swap1(HN.x); HS.y = swap1(HN.y);   // partner h
        // Next-step h-partials: off the critical path (full step of slack).
        P[l][0] = vfma_(HS, sp(whx[l][0]), vfma_(HN, sp(who[l][0]), sp(bi[l][0])));
        P[l][1] = vfma_(HS, sp(whx[l][1]), vfma_(HN, sp(who[l][1]), sp(bi[l][1])));
        P[l][2] = vfma_(HS, sp(whx[l][2]), vfma_(HN, sp(who[l][2]), sp(bi[l][2])));
        P[l][3] = vfma_(HS, sp(whx[l][3]), vfma_(HN, sp(who[l][3]), sp(bi[l][3])));
        XO = HN; XX = HS;
      }
      lds[el][tl*NH + j]      = XO.x;      // stage layer-3 h_j, chain A
      lds[32 + el][tl*NH + j] = XO.y;      // chain B
    }
    __syncthreads();
    // Coalesced flush (scalar LDS reads: rows are 17 floats, not 16B-aligned).
    #pragma unroll
    for (int q = 0; q < 4; ++q) {
      const int f = q*64 + tid, e = f >> 2, p = f & 3;
      float4 v;
      v.x = lds[e][p*4 + 0]; v.y = lds[e][p*4 + 1];
      v.z = lds[e][p*4 + 2]; v.w = lds[e][p*4 + 3];
      float4* o4 = (float4*)(out + (size_t)(b0 + e) * (NT*NH) + (size_t)t0*NH);
      o4[p] = v;
      float d0 = v.x - lv[q].x, d1 = v.y - lv[q].y,
            d2 = v.z - lv[q].z, d3 = v.w - lv[q].w;
      lsum = fmaf(d0,d0, fmaf(d1,d1, fmaf(d2,d2, fmaf(d3,d3, lsum))));
    }
    __syncthreads();
  }

  #pragma unroll
  for (int off = 32; off >= 1; off >>= 1)
    lsum += __shfl_xor(lsum, off, 64);
  if (tid == 0)
    atomicAdd(out + NRET, lsum * (1.0f / (float)NRET));
}

extern "C" void kernel_launch(void* const* d_in, const int* in_sizes, int n_in,
                              void* d_out, int out_size, void* d_ws, size_t ws_size,
                              hipStream_t stream) {
  const float* inp = (const float*)d_in[0];
  const float* lab = (const float*)d_in[1];
  const float* Wih = (const float*)d_in[2];
  const float* Whh = (const float*)d_in[3];
  const float* bhh = (const float*)d_in[4];
  float* out = (float*)d_out;
  // loss slot must be re-zeroed every launch (harness does not re-poison)
  (void)hipMemsetAsync(out + NRET, 0, sizeof(float), stream);
  lstm_k<<<NB/64, 64, 0, stream>>>(inp, lab, Wih, Whh, bhh, out);
}

// Round 6
// 171.385 us; speedup vs baseline: 2.0983x; 1.7654x over previous
//
#include <hip/hip_runtime.h>

#define NB 16384
#define NT 512
#define NL 4
#define NRET (NB*NT*2)
#define TC 8

// DPP quad-perm helpers (compile-time ctrl).
template<int CTRL> __device__ __forceinline__ float dppf(float x) {
  return __int_as_float(__builtin_amdgcn_mov_dpp(__float_as_int(x), CTRL, 0xF, 0xF, true));
}
#define QP_SWAP  0xB1  // [1,0,3,2]: pair-partner swap (L0<->L1, L2<->L3)
#define QP_OWN   0xA0  // [0,0,2,2]: bcast L0->L0,L1 ; L2->L2,L3
#define QP_OTH   0x0A  // [2,2,0,0]: bcast L2->L0,L1 ; L0->L2,L3

// One chain per QUAD of lanes: lane (unit j = ql>>1, pair p = ql&1).
// p=0 lane owns sigma-rows (i_j, f_j); p=1 lane owns (g_j [tanh], o_j).
// Per cell-step the WAVE issues only 5 transcendentals for its 16 chains
// (2 gate exp2, 1 shared gate rcp, 1 cell exp2, 1 cell rcp). R2..R5 fit:
// wall/cell ~= 2*VALU + 16*TRANS per wave -> 2*24 + 16*5 = 128 cy/cell
// vs R2's 214. 16384/16 = 1024 waves = 1 per SIMD (idle SIMDs were free).
__global__ __launch_bounds__(64, 1) void lstm_k(
    const float* __restrict__ inp, const float* __restrict__ lab,
    const float* __restrict__ Wih, const float* __restrict__ Whh,
    const float* __restrict__ bhh, float* __restrict__ out)
{
  __shared__ float lds[16][TC*2 + 1];      // 16 chains x 8 steps x 2 (+pad)
  const int tid = threadIdx.x;
  const int ql  = tid & 3;                 // position in quad
  const int jl  = ql >> 1;                 // unit owned by this lane-pair
  const int gp  = ql & 1;                  // 0: (i,f) rows, 1: (g,o) rows
  const int b0  = blockIdx.x << 4;         // 16 chains per block
  const int b   = b0 + (tid >> 2);

  const float K1 = 1.4426950408889634f;    // log2(e)
  const float K2 = 2.8853900817779268f;    // 2 log2(e)

  // Per-lane weights: reg-a row = gp? g_jl : i_jl ; reg-b row = gp? o_jl : f_jl.
  // sigma rows x(-log2e) => sigma = rcp(1+exp2(g~)); tanh row x(-2log2e) =>
  // e = exp(-2g), tanh=(1-e)/(1+e). The -2log2e OUTPUT scale for tanh(g)
  // folds into (pa,qa), so c~ = -2log2e*c and tanh(c) needs no input mul.
  float wxAa[NL], wxBa[NL], whAa[NL], whBa[NL], ba[NL];
  float wxAb[NL], wxBb[NL], whAb[NL], whBb[NL], bb[NL];
  #pragma unroll
  for (int l = 0; l < NL; ++l) {
    const int gA = gp ? 2 : 0, gB = gp ? 3 : 1;
    const int rA = l*8 + gA*2 + jl, rB = l*8 + gB*2 + jl;
    const float sA = gp ? -K2 : -K1, sB = -K1;
    wxAa[l] = sA * Wih[rA*2 + jl];  wxBa[l] = sA * Wih[rA*2 + (1-jl)];
    whAa[l] = sA * Whh[rA*2 + jl];  whBa[l] = sA * Whh[rA*2 + (1-jl)];
    ba[l]   = sA * bhh[rA];
    wxAb[l] = sB * Wih[rB*2 + jl];  wxBb[l] = sB * Wih[rB*2 + (1-jl)];
    whAb[l] = sB * Whh[rB*2 + jl];  whBb[l] = sB * Whh[rB*2 + (1-jl)];
    bb[l]   = sB * bhh[rB];
  }
  const float pa = gp ? -K2 : 1.0f;        // va = (pa + qa*ea)/(1+ea):
  const float qa = gp ?  K2 : 0.0f;        // sigma -> 1/(1+e); g -> -K2*tanh(g)
  // Pin weights: forbid remat-from-global inside the recurrence (R1 lesson).
  #pragma unroll
  for (int l = 0; l < NL; ++l) {
    asm volatile("" :
      "+v"(wxAa[l]), "+v"(wxBa[l]), "+v"(whAa[l]), "+v"(whBa[l]), "+v"(ba[l]),
      "+v"(wxAb[l]), "+v"(wxBb[l]), "+v"(whAb[l]), "+v"(whBb[l]), "+v"(bb[l]));
  }

  float prta[NL], prtb[NL], cs[NL];
  #pragma unroll
  for (int l = 0; l < NL; ++l) { prta[l] = ba[l]; prtb[l] = bb[l]; cs[l] = 0.f; }

  float xA = inp[b*2 + jl];                // own-unit input component
  float xB = inp[b*2 + (1-jl)];            // other-unit component
  float lsum = 0.f;
  const int e = tid >> 2, p = tid & 3;

  for (int t0 = 0; t0 < NT; t0 += TC) {
    // Label prefetch: ~1000 cy of compute covers HBM latency before flush.
    float4 lv = ((const float4*)(lab + (size_t)(b0 + e)*(NT*2) + (size_t)t0*2))[p];

    #pragma unroll
    for (int tl = 0; tl < TC; ++tl) {
      #pragma unroll
      for (int l = 0; l < NL; ++l) {
        float ga = fmaf(wxAa[l], xA, fmaf(wxBa[l], xB, prta[l]));
        float gb = fmaf(wxAb[l], xA, fmaf(wxBb[l], xB, prtb[l]));
        float ea = __builtin_amdgcn_exp2f(ga);
        float eb = __builtin_amdgcn_exp2f(gb);
        float da = 1.f + ea, db = 1.f + eb;
        float r  = __builtin_amdgcn_rcpf(da * db);   // ONE rcp for both rows
        float u  = db * r;                           // 1/da
        float vb = da * r;                           // 1/db  (sigma: f or o)
        float va = fmaf(qa, ea, pa) * u;             // sigma_i or -K2*tanh(g)
        float tg = dppf<QP_SWAP>(va);                // p0 lane <- -K2*tanh(g)
        float vo = dppf<QP_SWAP>(vb);                // p0 lane <- sigma_o
        float c2 = fmaf(vb, cs[l], va * tg);         // scaled c (real on p0)
        float ec = __builtin_amdgcn_exp2f(c2);       // exp(-2c)
        float rc = __builtin_amdgcn_rcpf(1.f + ec);
        float th = fmaf(-ec, rc, rc);                // tanh(c)
        float h  = vo * th;                          // real only on p0 lanes
        float hA = dppf<QP_OWN>(h);                  // h_own-unit to all lanes
        float hB = dppf<QP_OTH>(h);                  // h_other-unit
        prta[l] = fmaf(whAa[l], hA, fmaf(whBa[l], hB, ba[l]));
        prtb[l] = fmaf(whAb[l], hA, fmaf(whBb[l], hB, bb[l]));
        cs[l] = c2;
        xA = hA; xB = hB;
      }
      if (gp == 0) lds[tid >> 2][tl*2 + jl] = xA;    // layer-3 h_j (p0 lanes)
    }
    __syncthreads();
    // Coalesced flush: 64 float4 = 16 chains x 16 floats; fused sq-err.
    float4 v;
    v.x = lds[e][p*4 + 0]; v.y = lds[e][p*4 + 1];
    v.z = lds[e][p*4 + 2]; v.w = lds[e][p*4 + 3];
    ((float4*)(out + (size_t)(b0 + e)*(NT*2) + (size_t)t0*2))[p] = v;
    float d0 = v.x - lv.x, d1 = v.y - lv.y, d2 = v.z - lv.z, d3 = v.w - lv.w;
    lsum = fmaf(d0,d0, fmaf(d1,d1, fmaf(d2,d2, fmaf(d3,d3, lsum))));
    __syncthreads();
  }

  #pragma unroll
  for (int off = 32; off >= 1; off >>= 1)
    lsum += __shfl_xor(lsum, off, 64);
  if (tid == 0)
    atomicAdd(out + NRET, lsum * (1.0f / (float)NRET));
}

extern "C" void kernel_launch(void* const* d_in, const int* in_sizes, int n_in,
                              void* d_out, int out_size, void* d_ws, size_t ws_size,
                              hipStream_t stream) {
  const float* inp = (const float*)d_in[0];
  const float* lab = (const float*)d_in[1];
  const float* Wih = (const float*)d_in[2];
  const float* Whh = (const float*)d_in[3];
  const float* bhh = (const float*)d_in[4];
  float* out = (float*)d_out;
  // loss slot must be re-zeroed every launch (harness does not re-poison)
  (void)hipMemsetAsync(out + NRET, 0, sizeof(float), stream);
  lstm_k<<<NB/16, 64, 0, stream>>>(inp, lab, Wih, Whh, bhh, out);
}